// Round 3
// baseline (200.151 us; speedup 1.0000x reference)
//
#include <hip/hip_runtime.h>
#include <hip/hip_bf16.h>

#define Hh 50

typedef __attribute__((ext_vector_type(8))) short bf16x8;
typedef __attribute__((ext_vector_type(4))) float f32x4;
typedef __attribute__((ext_vector_type(2))) float f32x2;

static __device__ __forceinline__ float bflo(unsigned int u) {
    unsigned int x = u << 16;
    return __builtin_bit_cast(float, x);
}
static __device__ __forceinline__ float bfhi(unsigned int u) {
    unsigned int x = u & 0xffff0000u;
    return __builtin_bit_cast(float, x);
}
static __device__ __forceinline__ short b16(float x) {
    return __builtin_bit_cast(short, __float2bfloat16(x));
}
// convert 8 contiguous f32 to a bf16x8 MFMA fragment
static __device__ __forceinline__ bf16x8 cvt8(const float* p) {
    f32x4 a = *(const f32x4*)p;
    f32x4 b = *(const f32x4*)(p + 4);
    bf16x8 r;
    r[0] = b16(a[0]); r[1] = b16(a[1]); r[2] = b16(a[2]); r[3] = b16(a[3]);
    r[4] = b16(b[0]); r[5] = b16(b[1]); r[6] = b16(b[2]); r[7] = b16(b[3]);
    return r;
}

// ---------------- Kernel 1: wc_out[4096][256] (f32) = cur @ wc_w^T + wc_b ----------------
__global__ __launch_bounds__(64) void k_wc(const float* __restrict__ cur,
                                           const float* __restrict__ wcw,
                                           const float* __restrict__ wcb,
                                           float* __restrict__ out) {
    int l = threadIdx.x;
    int m0 = (int)(blockIdx.x >> 2) * 16;
    int ntb = (int)(blockIdx.x & 3) * 4;
    int lk = (l >> 4) * 8;

    bf16x8 Af[8];
#pragma unroll
    for (int k = 0; k < 8; k++)
        Af[k] = cvt8(cur + (size_t)(m0 + (l & 15)) * 256 + k * 32 + lk);

#pragma unroll
    for (int nt = 0; nt < 4; nt++) {
        int col = (ntb + nt) * 16 + (l & 15);
        f32x4 a = {0.f, 0.f, 0.f, 0.f};
#pragma unroll
        for (int k = 0; k < 8; k++) {
            bf16x8 Bf = cvt8(wcw + (size_t)col * 256 + k * 32 + lk);
            a = __builtin_amdgcn_mfma_f32_16x16x32_bf16(Af[k], Bf, a, 0, 0, 0);
        }
        float bias = wcb[col];
        int row = m0 + (l >> 4) * 4;
#pragma unroll
        for (int r = 0; r < 4; r++)
            out[(size_t)(row + r) * 256 + col] = a[r] + bias;
    }
}

// ---------------- Kernel 2: fused wh GEMM + sigmoid + qt dot + alpha*hist ----------------
// One block handles (b, s0, s0+1). LDS A-tile rows interleaved: row = 2h + si.
__global__ __launch_bounds__(256, 2) void k_main(const float* __restrict__ hist,
                                                 const float* __restrict__ wc_ws,
                                                 const float* __restrict__ whw,
                                                 const float* __restrict__ whb,
                                                 const float* __restrict__ qtw,
                                                 const float* __restrict__ qtb,
                                                 float* __restrict__ hsum_ws) {
    __shared__ __align__(16) char histA[112 * 512];   // swizzled bf16 [row][256]
    __shared__ float wcrow[512];
    __shared__ float alphaP[4][128];
    __shared__ float alphaF[128];

    int tid = threadIdx.x;
    int l = tid & 63;
    int w = tid >> 6;
    int b = (int)(blockIdx.x >> 8);
    int s0 = (int)(blockIdx.x & 255) * 2;

    // preload wh_w^T fragments for this wave's 64 output cols (128 VGPRs)
    int bcol = w * 64;
    int lk = (l >> 4) * 8;
    bf16x8 Bf[4][8];
#pragma unroll
    for (int nt = 0; nt < 4; nt++)
#pragma unroll
        for (int k = 0; k < 8; k++)
            Bf[nt][k] = cvt8(whw + (size_t)(bcol + nt * 16 + (l & 15)) * 256 + k * 32 + lk);

    // stage hist rows (100 rows x 256 elems) into swizzled LDS as bf16
    for (int c = tid; c < 3200; c += 256) {
        int row = c >> 5;              // 0..99 = 2h+si
        int h = row >> 1, si = row & 1;
        bf16x8 v = cvt8(hist + ((size_t)(b * Hh + h) * 512 + (s0 + si)) * 256 + (c & 31) * 8);
        int off = row * 512 + (((c & 31) * 16) ^ ((row & 7) << 4));
        *(bf16x8*)(&histA[off]) = v;
    }
    // zero the 12 pad rows so mt=6 MFMAs read clean data
    for (int c2 = tid; c2 < 384; c2 += 256) {
        int row = 100 + (c2 >> 5);
        *(f32x4*)(&histA[row * 512 + (c2 & 31) * 16]) = (f32x4){0.f, 0.f, 0.f, 0.f};
    }
    {
        const float* wcp = wc_ws + (size_t)(b * 512 + s0) * 256;
        for (int t = tid; t < 512; t += 256) wcrow[t] = wcp[t];
    }
    __syncthreads();

    // per-lane epilogue constants
    float qv[4], wb0[4], wb1[4];
#pragma unroll
    for (int nt = 0; nt < 4; nt++) {
        int o = bcol + nt * 16 + (l & 15);
        float whbv = whb[o];
        qv[nt] = qtw[o];
        wb0[nt] = whbv + wcrow[o];
        wb1[nt] = whbv + wcrow[256 + o];
    }

    // MFMA main loop: 7 m-tiles x 4 n-tiles x 8 k-steps
    float pal[7][4];
#pragma unroll
    for (int mt = 0; mt < 7; mt++)
#pragma unroll
        for (int r = 0; r < 4; r++) pal[mt][r] = 0.f;

#pragma unroll
    for (int mt = 0; mt < 7; mt++) {
        int arow = mt * 16 + (l & 15);
        bf16x8 Af[8];
#pragma unroll
        for (int k = 0; k < 8; k++) {
            int off = arow * 512 + (((k * 64) + (l >> 4) * 16) ^ ((arow & 7) << 4));
            Af[k] = *(const bf16x8*)(&histA[off]);
        }
#pragma unroll
        for (int nt = 0; nt < 4; nt++) {
            f32x4 acc = {0.f, 0.f, 0.f, 0.f};
#pragma unroll
            for (int k = 0; k < 8; k++)
                acc = __builtin_amdgcn_mfma_f32_16x16x32_bf16(Af[k], Bf[nt][k], acc, 0, 0, 0);
#pragma unroll
            for (int r = 0; r < 4; r++) {
                float v = acc[r] + ((r & 1) ? wb1[nt] : wb0[nt]);
                float sg = 1.0f / (1.0f + __expf(-v));
                pal[mt][r] += qv[nt] * sg;
            }
        }
    }

    // reduce partial alphas over the 16 cols held per row-group
#pragma unroll
    for (int mt = 0; mt < 7; mt++) {
#pragma unroll
        for (int r = 0; r < 4; r++) {
            float v = pal[mt][r];
            v += __shfl_xor(v, 1);
            v += __shfl_xor(v, 2);
            v += __shfl_xor(v, 4);
            v += __shfl_xor(v, 8);
            if ((l & 15) == 0) alphaP[w][mt * 16 + (l >> 4) * 4 + r] = v;
        }
    }
    __syncthreads();
    if (tid < 112) {
        alphaF[tid] = qtb[0] + alphaP[0][tid] + alphaP[1][tid] + alphaP[2][tid] + alphaP[3][tid];
    }
    __syncthreads();

    // history_sum = sum_h alpha[row] * hist[row], from LDS; f32 out
    {
        int d2 = tid & 127;
        int si = tid >> 7;
        float a0 = 0.f, a1 = 0.f;
        for (int h = 0; h < Hh; h++) {
            int row = 2 * h + si;
            unsigned int u = *(const unsigned int*)(&histA[row * 512 + ((d2 * 4) ^ ((row & 7) << 4))]);
            float a = alphaF[row];
            a0 += a * bflo(u);
            a1 += a * bfhi(u);
        }
        f32x2 hv = {a0, a1};
        *(f32x2*)(hsum_ws + (size_t)(b * 512 + s0 + si) * 256 + d2 * 2) = hv;
    }
}

// ---------------- Kernel 3: out[4096][128] (f32) = [cur, hsum] @ wf_w^T + wf_b ----------------
__global__ __launch_bounds__(64) void k_wf(const float* __restrict__ cur,
                                           const float* __restrict__ hsum,
                                           const float* __restrict__ wfw,
                                           const float* __restrict__ wfb,
                                           float* __restrict__ out) {
    int l = threadIdx.x;
    int m0 = (int)(blockIdx.x >> 1) * 16;
    int ntb = (int)(blockIdx.x & 1) * 4;
    int lk = (l >> 4) * 8;

    f32x4 acc[4];
#pragma unroll
    for (int nt = 0; nt < 4; nt++) acc[nt] = (f32x4){0.f, 0.f, 0.f, 0.f};

#pragma unroll
    for (int k = 0; k < 16; k++) {
        int row = m0 + (l & 15);
        bf16x8 Af;
        if (k < 8)
            Af = cvt8(cur + (size_t)row * 256 + k * 32 + lk);
        else
            Af = cvt8(hsum + (size_t)row * 256 + (k - 8) * 32 + lk);
#pragma unroll
        for (int nt = 0; nt < 4; nt++) {
            int col = (ntb + nt) * 16 + (l & 15);
            bf16x8 Bf = cvt8(wfw + (size_t)col * 512 + k * 32 + lk);
            acc[nt] = __builtin_amdgcn_mfma_f32_16x16x32_bf16(Af, Bf, acc[nt], 0, 0, 0);
        }
    }
#pragma unroll
    for (int nt = 0; nt < 4; nt++) {
        int col = (ntb + nt) * 16 + (l & 15);
        float bias = wfb[col];
        int row = m0 + (l >> 4) * 4;
#pragma unroll
        for (int r = 0; r < 4; r++)
            out[(size_t)(row + r) * 128 + col] = acc[nt][r] + bias;
    }
}

extern "C" void kernel_launch(void* const* d_in, const int* in_sizes, int n_in,
                              void* d_out, int out_size, void* d_ws, size_t ws_size,
                              hipStream_t stream) {
    const float* hist = (const float*)d_in[0];
    const float* cur  = (const float*)d_in[1];
    const float* wc_w = (const float*)d_in[2];
    const float* wc_b = (const float*)d_in[3];
    const float* wh_w = (const float*)d_in[4];
    const float* wh_b = (const float*)d_in[5];
    const float* qt_w = (const float*)d_in[6];
    const float* qt_b = (const float*)d_in[7];
    const float* wf_w = (const float*)d_in[8];
    const float* wf_b = (const float*)d_in[9];

    float* wc_ws = (float*)d_ws;                                   // 4096*256 f32 = 4 MB
    float* hsum  = (float*)((char*)d_ws + ((size_t)4 << 20));      // 4096*256 f32 = 4 MB

    k_wc<<<1024, 64, 0, stream>>>(cur, wc_w, wc_b, wc_ws);
    k_main<<<2048, 256, 0, stream>>>(hist, wc_ws, wh_w, wh_b, qt_w, qt_b, hsum);
    k_wf<<<512, 64, 0, stream>>>(cur, hsum, wf_w, wf_b, (float*)d_out);
}